// Round 17
// baseline (126.035 us; speedup 1.0000x reference)
//
#include <hip/hip_runtime.h>
#include <hip/hip_bf16.h>
#include <stdint.h>

#define DEV __device__ __forceinline__

typedef unsigned short u16;
typedef unsigned char u8;
typedef __attribute__((ext_vector_type(8))) short bf16x8;        // 8 bf16 MFMA A/B frag
typedef __attribute__((ext_vector_type(4))) float f32x4;         // MFMA C/D frag
typedef __attribute__((ext_vector_type(4))) int i32x4;           // i8 MFMA frag / acc

DEV u16 bf(float v) {
  __hip_bfloat16 h = __float2bfloat16(v);
  union { __hip_bfloat16 h; u16 u; } x; x.h = h;
  return x.u;
}

DEV signed char qi8(float v) {
  float t = fminf(fmaxf(v * 31.75f, -127.f), 127.f);   // scale 127/4
  return (signed char)(int)rintf(t);
}

DEV void gld_lds(const void* g, void* l) {
  __builtin_amdgcn_global_load_lds(
      (const __attribute__((address_space(1))) uint32_t*)g,
      (__attribute__((address_space(3))) uint32_t*)l, 16, 0, 0);
}

// ---------------- f32 -> bf16 conversion (Wq, Wv only — x is fused into proj)
__global__ void conv_w(const float* __restrict__ Wq,
                       const float* __restrict__ Wv,
                       u16* __restrict__ wqb,
                       u16* __restrict__ wvb) {
  const int NW4 = (512 * 512) / 4;
  int i = blockIdx.x * blockDim.x + threadIdx.x;     // grid 512*256 = 2*NW4
  const float4* src; u16* dst; int off;
  if (i < NW4) { src = (const float4*)Wq; dst = wqb; off = i; }
  else         { src = (const float4*)Wv; dst = wvb; off = i - NW4; }
  float4 f = src[off];
  ((ushort4*)dst)[off] = make_ushort4(bf(f.x), bf(f.y), bf(f.z), bf(f.w));
}

// ---------------- fused projection GEMM: [q | v] in one pass ---------------
// A = x (f32, converted in-kernel): reg-staged (8 float4/thread/iter, compiler
// schedules loads; cvt -> ds_write_b128 with source-slot XOR pre-applied so
// the unchanged XOR read side sees true k-slots — rule #21 both-sides).
// B = W (bf16 via conv_w): gld_lds as before. Double-buffered, 1 barrier/iter.
__global__ __launch_bounds__(256, 2)
void gemm_proj(const float* __restrict__ x,          // f32 [16384][512]
               const u16* __restrict__ wqb,
               const u16* __restrict__ wvb,
               const float* __restrict__ bq,
               const float* __restrict__ bv,
               signed char* __restrict__ qb8,
               signed char* __restrict__ vT8) {
  constexpr int BK = 64, NBN = 8, NBM = 128;
  constexpr int TILE = 256 * 64;            // u16 per buffer (A 128x64 | B 128x64)
  __shared__ u16 lds[2 * TILE];             // 64 KB

  const int tid  = threadIdx.x;
  const int lane = tid & 63;
  const int w    = tid >> 6;
  const int wr   = w >> 1, wc = w & 1;

  const int nwg = (int)gridDim.x;           // 1024
  const int id  = blockIdx.x;
  const int swz = (id & 7) * (nwg >> 3) + (id >> 3);
  const int bn  = swz % NBN;
  const int bm  = (swz / NBN) % NBM;

  const u16* B = (bn < 4) ? wqb + (long)bn * 128 * 512
                          : wvb + (long)(bn - 4) * 128 * 512;

  const int lrow = lane & 15;
  const int rx   = lane & 7;
  const int srow = lane >> 3;
  const int scol = ((lane & 7) ^ srow) << 3;      // u16 units, pre-swizzled slot

  // B staging: 16 chunks x 1KB (8 rows x 64 u16); 4 chunks/wave
  const u16* bsrc[4];
#pragma unroll
  for (int c = 0; c < 4; ++c) {
    int brow = (w * 4 + c) * 8 + srow;            // 0..127
    bsrc[c] = B + (long)brow * 512 + scol;
  }

  // A staging: thread owns row ar, half hv (4 x 16B slots)
  const int ar = tid >> 1, hv = tid & 1;
  const float* asrc[4];
#pragma unroll
  for (int i = 0; i < 4; ++i) {
    int s = (hv * 4 + i) ^ (ar & 7);              // pre-swizzled source slot
    asrc[i] = x + (long)(bm * 128 + ar) * 512 + 8 * s;
  }

  f32x4 acc[4][4] = {};

  // prologue: tile 0
  {
    float4 a[4], b4[4];
#pragma unroll
    for (int i = 0; i < 4; ++i) {
      a[i]  = *(const float4*)(asrc[i]);
      b4[i] = *(const float4*)(asrc[i] + 4);
    }
#pragma unroll
    for (int c = 0; c < 4; ++c)
      gld_lds(bsrc[c], &lds[128 * 64 + (w * 4 + c) * 512]);
#pragma unroll
    for (int i = 0; i < 4; ++i) {
      bf16x8 pk;
      pk[0] = bf(a[i].x);  pk[1] = bf(a[i].y);  pk[2] = bf(a[i].z);  pk[3] = bf(a[i].w);
      pk[4] = bf(b4[i].x); pk[5] = bf(b4[i].y); pk[6] = bf(b4[i].z); pk[7] = bf(b4[i].w);
      *(bf16x8*)&lds[ar * 64 + (hv * 4 + i) * 8] = pk;
    }
    __syncthreads();
  }

  int p = 0;
  for (int kt = 0; kt < 8; ++kt) {
    float4 a[4], b4[4];
    if (kt + 1 < 8) {
#pragma unroll
      for (int i = 0; i < 4; ++i) {
        a[i]  = *(const float4*)(asrc[i] + (kt + 1) * 64);
        b4[i] = *(const float4*)(asrc[i] + (kt + 1) * 64 + 4);
      }
#pragma unroll
      for (int c = 0; c < 4; ++c)
        gld_lds(bsrc[c] + (kt + 1) * BK,
                &lds[(p ^ 1) * TILE + 128 * 64 + (w * 4 + c) * 512]);
    }

    const u16* Alds = &lds[p * TILE];
    const u16* Blds = &lds[p * TILE + 128 * 64];
#pragma unroll
    for (int ks = 0; ks < 2; ++ks) {
      const int sl = ((ks * 4 + (lane >> 4)) ^ rx) << 3;
      bf16x8 af[4], bfr[4];
#pragma unroll
      for (int t = 0; t < 4; ++t) {
        af[t]  = *(const bf16x8*)&Alds[(wr * 64 + t * 16 + lrow) * BK + sl];
        bfr[t] = *(const bf16x8*)&Blds[(wc * 64 + t * 16 + lrow) * BK + sl];
      }
#pragma unroll
      for (int mt = 0; mt < 4; ++mt)
#pragma unroll
        for (int nt = 0; nt < 4; ++nt)
          acc[mt][nt] = __builtin_amdgcn_mfma_f32_16x16x32_bf16(af[mt], bfr[nt], acc[mt][nt], 0, 0, 0);
    }

    if (kt + 1 < 8) {
#pragma unroll
      for (int i = 0; i < 4; ++i) {
        bf16x8 pk;
        pk[0] = bf(a[i].x);  pk[1] = bf(a[i].y);  pk[2] = bf(a[i].z);  pk[3] = bf(a[i].w);
        pk[4] = bf(b4[i].x); pk[5] = bf(b4[i].y); pk[6] = bf(b4[i].z); pk[7] = bf(b4[i].w);
        *(bf16x8*)&lds[(p ^ 1) * TILE + ar * 64 + (hv * 4 + i) * 8] = pk;
      }
    }
    __syncthreads();
    p ^= 1;
  }

  const int row0 = bm * 128 + wr * 64;
  const int rsub = (lane >> 4) << 2;

  if (bn < 4) {   // q half: row-major i8, bias per col
#pragma unroll
    for (int mt = 0; mt < 4; ++mt)
#pragma unroll
      for (int nt = 0; nt < 4; ++nt) {
        int col = bn * 128 + wc * 64 + nt * 16 + lrow;
        float b = bq[col];
#pragma unroll
        for (int r = 0; r < 4; ++r)
          qb8[(long)(row0 + mt * 16 + rsub + r) * 512 + col] = qi8(acc[mt][nt][r] + b);
      }
  } else {        // v half: transposed packed store into vT8[e][m]
#pragma unroll
    for (int mt = 0; mt < 4; ++mt)
#pragma unroll
      for (int nt = 0; nt < 4; ++nt) {
        int e = (bn - 4) * 128 + wc * 64 + nt * 16 + lrow;
        float b = bv[e];
        int rowb = row0 + mt * 16 + rsub;
        uint32_t pk = ((uint32_t)(u8)qi8(acc[mt][nt][0] + b)) |
                      ((uint32_t)(u8)qi8(acc[mt][nt][1] + b) << 8) |
                      ((uint32_t)(u8)qi8(acc[mt][nt][2] + b) << 16) |
                      ((uint32_t)(u8)qi8(acc[mt][nt][3] + b) << 24);
        *(uint32_t*)&vT8[(long)e * 16384 + rowb] = pk;
      }
  }
}

// ---------------- symmetric sigmoid(QQ^T) i8 GEMM -> u8 P ------------------
// 256(M)x128(N) macro-tile; 8 waves (4x2), wave tile 64x64.
// launch_bounds (512,4): (512,6) forces VGPR<=85 -> acc spills (r15). Keep 4.
// Pass-2 merged: both halves bounce in one round (rows 0-127 = h0 transpose,
// 128-255 = h1), 1 barrier instead of 4.
__global__ __launch_bounds__(512, 4)
void gemm_sym_sig_i8(const signed char* __restrict__ Q, long sQz,
                     u8* __restrict__ P, long sPz) {
  __shared__ u8 lds[49152];                 // 48 KB: staging 384x128 | bounce 256x144

  const int tid  = threadIdx.x;
  const int lane = tid & 63;
  const int w    = tid >> 6;                // 0..7
  const int wr   = w >> 1, wc = w & 1;      // 4 x 2

  const int nwg = (int)gridDim.x;           // 1088
  const int id  = blockIdx.x;
  const int swz = (id & 7) * (nwg >> 3) + (id >> 3);
  const int z   = swz / 272;
  int rem = swz % 272;
  int m = 0;
  while (rem >= 32 - 2 * m) { rem -= 32 - 2 * m; ++m; }
  const int n = 2 * m + rem;                // col block (128-units), n >= 2m

  const int R0 = m * 256;                   // global row base
  const int C0 = n * 128;                   // global col base
  const signed char* Qz = Q + (long)z * sQz;

  const int lrow = lane & 15;
  const int rx   = lane & 7;
  const int srow = lane >> 3;                     // row within 8-row chunk
  const int scol = ((lane & 7) ^ srow) << 4;      // pre-swizzled 16B slot (of 8)

  // staging: 48 chunks x 1KB (8 rows x 128 B); 6 chunks/wave
  const signed char* srcs[6];
#pragma unroll
  for (int c = 0; c < 6; ++c) {
    int row = (w * 6 + c) * 8 + srow;             // 0..383 (A:0-255 | B:256-383)
    srcs[c] = (row < 256)
        ? Qz + (long)(R0 + row) * 512 + scol
        : Qz + (long)(C0 + (row - 256)) * 512 + scol;
  }

  i32x4 acc[4][4] = {};

  for (int kt = 0; kt < 4; ++kt) {                // BK = 128 bytes
#pragma unroll
    for (int c = 0; c < 6; ++c)
      gld_lds(srcs[c] + kt * 128, &lds[(w * 6 + c) * 1024]);
    __syncthreads();

#pragma unroll
    for (int ks = 0; ks < 2; ++ks) {              // two 64B k-slices
      const int sl = ((ks * 4 + (lane >> 4)) ^ rx) << 4;
      i32x4 af[4], bfv[4];
#pragma unroll
      for (int t = 0; t < 4; ++t) {
        af[t]  = *(const i32x4*)&lds[(wr * 64 + t * 16 + lrow) * 128 + sl];
        bfv[t] = *(const i32x4*)&lds[256 * 128 + (wc * 64 + t * 16 + lrow) * 128 + sl];
      }
      __builtin_amdgcn_s_setprio(1);
#pragma unroll
      for (int mt = 0; mt < 4; ++mt)
#pragma unroll
        for (int nt = 0; nt < 4; ++nt)
          acc[mt][nt] = __builtin_amdgcn_mfma_i32_16x16x64_i8(af[mt], bfv[nt], acc[mt][nt], 0, 0, 0);
      __builtin_amdgcn_s_setprio(0);
    }
    __syncthreads();
  }

  u8* Pz = P + (long)z * sPz;
  const int rsub = (lane >> 4) << 2;
  const int rl = wr * 64 + rsub;            // local row base (+mt*16, +r)
  const int cl = wc * 64 + lrow;            // local col base (+nt*16)

  // sigmoid(dequant) -> u8, packed 4 rows per u32. Constant fold:
  // (4/127)^2 * log2(e)/sqrt(512) = 6.324483e-5 -> one mul into exp2 arg.
  uint32_t sbp[4][4];
#pragma unroll
  for (int mt = 0; mt < 4; ++mt)
#pragma unroll
    for (int nt = 0; nt < 4; ++nt) {
      uint32_t pk = 0;
#pragma unroll
      for (int r = 0; r < 4; ++r) {
        float e = __builtin_amdgcn_exp2f((float)acc[mt][nt][r] * -6.324483e-5f);
        float pr = __builtin_amdgcn_rcpf(1.0f + e);
        pk |= (uint32_t)(u8)(int)(pr * 127.f + 0.5f) << (8 * r);
      }
      sbp[mt][nt] = pk;
    }

  const int sslot = tid & 7;               // 16B slot within 128B row
  const int srow2 = tid >> 3;              // 0..63

  // pass 1: normal orientation bounce (256x144) -> dense 16B row stores
#pragma unroll
  for (int mt = 0; mt < 4; ++mt)
#pragma unroll
    for (int nt = 0; nt < 4; ++nt) {
      uint32_t pk = sbp[mt][nt];
#pragma unroll
      for (int r = 0; r < 4; ++r)
        lds[(rl + mt * 16 + r) * 144 + cl + nt * 16] = (u8)(pk >> (8 * r));
    }
  __syncthreads();
#pragma unroll
  for (int j = 0; j < 4; ++j) {            // rows j*64 .. j*64+63; half = j>>1
    int row = j * 64 + srow2;
    if (j < 2 || n > 2 * m) {              // store iff n >= 2m + half
      uint4 v = *(const uint4*)&lds[row * 144 + sslot * 16];
      *(uint4*)&Pz[(long)(R0 + row) * 4096 + C0 + sslot * 16] = v;
    }
  }

  // pass 2 (merged halves): transposed tiles; h=0 -> bounce rows 0-127,
  // h=1 -> rows 128-255. Write iff n > 2m+h; one barrier pair total.
  if (n > 2 * m) {
    __syncthreads();                       // pass-1 bounce reads complete
    const int h = wr >> 1;                 // this wave's half
    if (n > 2 * m + h) {
#pragma unroll
      for (int mt = 0; mt < 4; ++mt)
#pragma unroll
        for (int nt = 0; nt < 4; ++nt)
          *(uint32_t*)&lds[(128 * h + cl + nt * 16) * 144 + (rl - 128 * h + mt * 16)] = sbp[mt][nt];
    }
    __syncthreads();
#pragma unroll
    for (int j = 0; j < 4; ++j) {
      int row = j * 64 + srow2;            // 0..255
      int hh = row >> 7;
      if (n > 2 * m + hh) {
        uint4 v = *(const uint4*)&lds[row * 144 + sslot * 16];
        *(uint4*)&Pz[(long)(C0 + (row & 127)) * 4096 + R0 + 128 * hh + sslot * 16] = v;
      }
    }
  }
}

// ---------------- O = (SP*SV) * P_u8 @ vT_i8^T, i8 MFMA, BK=128 ------------
// 128x128 tile, 4 waves (2x2), wave tile 64x64, 2 blocks/CU (r13: 34 us).
__global__ __launch_bounds__(256, 2)
void gemm_pv_i8(const signed char* __restrict__ A,   // P [4*4096][4096] (u8 vals)
                const signed char* __restrict__ B,   // vT_i8 [512][16384]
                float* __restrict__ C) {             // out [4*4096][512]
  constexpr int NBN = 4, NBM = 32;
  constexpr int TILE = 256 * 128;         // bytes per buffer (32 KB)
  __shared__ signed char lds[2 * TILE];   // 64 KB

  const int tid  = threadIdx.x;
  const int lane = tid & 63;
  const int w    = tid >> 6;              // 0..3
  const int wr   = w >> 1, wc = w & 1;

  const int nwg = (int)gridDim.x;
  const int id  = blockIdx.x;
  const int swz = (id & 7) * (nwg >> 3) + (id >> 3);
  const int bn  = swz % NBN;
  const int t0  = swz / NBN;
  const int bm  = t0 % NBM;
  const int z   = t0 / NBM;

  const signed char* Az = A + (long)z * 4096 * 4096;
  const signed char* Bz = B + (long)z * 4096;
  float* Cz = C + (long)z * 4096 * 512;

  const int lrow = lane & 15;
  const int rx   = lane & 7;
  const int srow = lane >> 3;                     // row within 8-row chunk
  const int scol = ((lane & 7) ^ srow) << 4;      // pre-swizzled 16B slot (of 8)

  // staging: 32 chunks x 1KB (8 rows x 128 B); 8 chunks/wave
  const signed char* srcs[8];
#pragma unroll
  for (int c = 0; c < 8; ++c) {
    int row = (w * 8 + c) * 8 + srow;             // 0..255 (A:0-127 | B:128-255)
    srcs[c] = (row < 128)
        ? Az + (long)(bm * 128 + row) * 4096 + scol
        : Bz + (long)(bn * 128 + (row - 128)) * 16384 + scol;
  }

  i32x4 acc[4][4] = {};

  const int nk = 32;                              // 4096 / 128
#pragma unroll
  for (int c = 0; c < 8; ++c)
    gld_lds(srcs[c], &lds[(w * 8 + c) * 1024]);

  int p = 0;
  for (int kt = 0; kt < nk; ++kt) {
    if (kt + 1 < nk) {
#pragma unroll
      for (int c = 0; c < 8; ++c)
        gld_lds(srcs[c] + (kt + 1) * 128, &lds[(p ^ 1) * TILE + (w * 8 + c) * 1024]);
      asm volatile("s_waitcnt vmcnt(8)" ::: "memory");
    } else {
      asm volatile("s_waitcnt vmcnt(0)" ::: "memory");
    }
    __builtin_amdgcn_s_barrier();
    asm volatile("" ::: "memory");

    const signed char* Al = &lds[p * TILE];
    const signed char* Bl = &lds[p * TILE + 128 * 128];
#pragma unroll
    for (int ks = 0; ks < 2; ++ks) {              // two 64B k-slices
      const int sl = ((ks * 4 + (lane >> 4)) ^ rx) << 4;
      i32x4 af[4], bfv[4];
#pragma unroll
      for (int t = 0; t < 4; ++t) {
        af[t]  = *(const i32x4*)&Al[(wr * 64 + t * 16 + lrow) * 128 + sl];
        bfv[t] = *(const i32x4*)&Bl[(wc * 64 + t * 16 + lrow) * 128 + sl];
      }
      __builtin_amdgcn_s_setprio(1);
#pragma unroll
      for (int mt = 0; mt < 4; ++mt)
#pragma unroll
        for (int nt = 0; nt < 4; ++nt)
          acc[mt][nt] = __builtin_amdgcn_mfma_i32_16x16x64_i8(af[mt], bfv[nt], acc[mt][nt], 0, 0, 0);
      __builtin_amdgcn_s_setprio(0);
    }

    asm volatile("" ::: "memory");
    __builtin_amdgcn_s_barrier();
    p ^= 1;
  }

  // epilogue: scale by SP*SV = (1/127)*(4/127)
  const float SC = 4.0f / 16129.0f;
  const int row0 = bm * 128 + wr * 64;
  const int col0 = bn * 128 + wc * 64;
  const int rsub = (lane >> 4) << 2;
#pragma unroll
  for (int mt = 0; mt < 4; ++mt)
#pragma unroll
    for (int nt = 0; nt < 4; ++nt)
#pragma unroll
      for (int r = 0; r < 4; ++r)
        Cz[(long)(row0 + mt * 16 + rsub + r) * 512 + col0 + nt * 16 + lrow] =
            SC * (float)acc[mt][nt][r];
}

// ---------------- launch ----------------
extern "C" void kernel_launch(void* const* d_in, const int* in_sizes, int n_in,
                              void* d_out, int out_size, void* d_ws, size_t ws_size,
                              hipStream_t stream) {
  const float* x  = (const float*)d_in[0];   // [4,4096,512]
  const float* Wq = (const float*)d_in[1];   // [512,512]
  const float* bq = (const float*)d_in[2];   // [512]
  const float* Wv = (const float*)d_in[3];   // [512,512]
  const float* bv = (const float*)d_in[4];   // [512]
  float* out = (float*)d_out;                // [4,4096,512] f32

  // workspace carve (~82 MB; xb eliminated)
  char* wsb = (char*)d_ws;
  signed char* qb8 = (signed char*)wsb;                   // [16384][512] i8   8 MB
  signed char* vT8 = (signed char*)(wsb + 8388608);       // [512][16384] i8   8 MB
  u16* wqb = (u16*)(wsb + 16777216);                      // [512][512] bf16
  u16* wvb = (u16*)(wsb + 17301504);                      // [512][512] bf16
  u8*  P8  = (u8*)(wsb + 17825792);                       // [4][4096][4096] u8 64 MB

  conv_w<<<512, 256, 0, stream>>>(Wq, Wv, wqb, wvb);

  // fused: q8 = qi8(x Wq^T + bq), vT8 = qi8(x Wv^T + bv)^T  (x f32 read direct)
  gemm_proj<<<1024, 256, 0, stream>>>(x, wqb, wvb, bq, bv, qb8, vT8);

  // P = round(127*sigmoid((4/127)^2 * q8 q8^T / sqrt(512))) u8, symmetric
  gemm_sym_sig_i8<<<1088, 512, 0, stream>>>(qb8, (long)4096 * 512,
                                            P8, (long)4096 * 4096);

  // O = (1/127)*(4/127) * P @ v
  gemm_pv_i8<<<512, 256, 0, stream>>>((const signed char*)P8, vT8, out);
}

// Round 18
// 114.407 us; speedup vs baseline: 1.1016x; 1.1016x over previous
//
#include <hip/hip_runtime.h>
#include <hip/hip_bf16.h>
#include <stdint.h>

#define DEV __device__ __forceinline__

typedef unsigned short u16;
typedef unsigned char u8;
typedef __attribute__((ext_vector_type(8))) short bf16x8;        // 8 bf16 MFMA A/B frag
typedef __attribute__((ext_vector_type(4))) float f32x4;         // MFMA C/D frag
typedef __attribute__((ext_vector_type(4))) int i32x4;           // i8 MFMA frag / acc

DEV u16 bf(float v) {
  __hip_bfloat16 h = __float2bfloat16(v);
  union { __hip_bfloat16 h; u16 u; } x; x.h = h;
  return x.u;
}

DEV signed char qi8(float v) {
  float t = fminf(fmaxf(v * 31.75f, -127.f), 127.f);   // scale 127/4
  return (signed char)(int)rintf(t);
}

DEV void gld_lds(const void* g, void* l) {
  __builtin_amdgcn_global_load_lds(
      (const __attribute__((address_space(1))) uint32_t*)g,
      (__attribute__((address_space(3))) uint32_t*)l, 16, 0, 0);
}

// ---------------- f32 -> bf16 conversion (x, Wq, Wv) ----------------
// (r17 lesson: fusing x-conversion into proj's staging loses global_load_lds
//  and adds ds_write conflicts — 14->56 us. Keep the separate pass.)
__global__ void conv_kernel(const float* __restrict__ x,
                            const float* __restrict__ Wq,
                            const float* __restrict__ Wv,
                            u16* __restrict__ xb,
                            u16* __restrict__ wqb,
                            u16* __restrict__ wvb) {
  const int NX4 = (16384 * 512) / 4;
  const int NW4 = (512 * 512) / 4;
  int i = blockIdx.x * blockDim.x + threadIdx.x;
  const float4* src; u16* dst; int off;
  if (i < NX4)            { src = (const float4*)x;  dst = xb;  off = i; }
  else if (i < NX4 + NW4) { src = (const float4*)Wq; dst = wqb; off = i - NX4; }
  else                    { src = (const float4*)Wv; dst = wvb; off = i - NX4 - NW4; }
  float4 f = src[off];
  ushort4 o = make_ushort4(bf(f.x), bf(f.y), bf(f.z), bf(f.w));
  ((ushort4*)dst)[off] = o;
}

// ---------------- fused projection GEMM: [q | v] in one pass ---------------
__global__ __launch_bounds__(256, 2)
void gemm_proj(const u16* __restrict__ xb,
               const u16* __restrict__ wqb,
               const u16* __restrict__ wvb,
               const float* __restrict__ bq,
               const float* __restrict__ bv,
               signed char* __restrict__ qb8,
               signed char* __restrict__ vT8) {
  constexpr int BK = 64, NBN = 8, NBM = 128;
  constexpr int TILE = 256 * 64;            // u16 per buffer
  __shared__ u16 lds[2 * TILE];             // 64 KB

  const int tid  = threadIdx.x;
  const int lane = tid & 63;
  const int w    = tid >> 6;
  const int wr   = w >> 1, wc = w & 1;

  const int nwg = (int)gridDim.x;           // 1024
  const int id  = blockIdx.x;
  const int swz = (id & 7) * (nwg >> 3) + (id >> 3);
  const int bn  = swz % NBN;
  const int bm  = (swz / NBN) % NBM;

  const u16* A = xb + (long)bm * 128 * 512;
  const u16* B = (bn < 4) ? wqb + (long)bn * 128 * 512
                          : wvb + (long)(bn - 4) * 128 * 512;

  const int lrow = lane & 15;
  const int rx   = lane & 7;
  const int srow = lane >> 3;
  const int scol = ((lane & 7) ^ srow) << 3;

  const u16* srcs[8];
#pragma unroll
  for (int c = 0; c < 8; ++c) {
    int row = (w * 8 + c) * 8 + srow;       // 0..255 (A | B)
    srcs[c] = (row < 128) ? A + (long)row * 512 + scol
                          : B + (long)(row - 128) * 512 + scol;
  }

  f32x4 acc[4][4] = {};

#pragma unroll
  for (int c = 0; c < 8; ++c)
    gld_lds(srcs[c], &lds[(w * 8 + c) * 512]);

  int p = 0;
  for (int kt = 0; kt < 8; ++kt) {
    if (kt + 1 < 8) {
#pragma unroll
      for (int c = 0; c < 8; ++c)
        gld_lds(srcs[c] + (kt + 1) * BK, &lds[(p ^ 1) * TILE + (w * 8 + c) * 512]);
      asm volatile("s_waitcnt vmcnt(8)" ::: "memory");
    } else {
      asm volatile("s_waitcnt vmcnt(0)" ::: "memory");
    }
    __builtin_amdgcn_s_barrier();
    asm volatile("" ::: "memory");

    const u16* Alds = &lds[p * TILE];
    const u16* Blds = &lds[p * TILE + 128 * 64];
#pragma unroll
    for (int ks = 0; ks < 2; ++ks) {
      const int sl = ((ks * 4 + (lane >> 4)) ^ rx) << 3;
      bf16x8 af[4], bfr[4];
#pragma unroll
      for (int t = 0; t < 4; ++t) {
        af[t]  = *(const bf16x8*)&Alds[(wr * 64 + t * 16 + lrow) * BK + sl];
        bfr[t] = *(const bf16x8*)&Blds[(wc * 64 + t * 16 + lrow) * BK + sl];
      }
#pragma unroll
      for (int mt = 0; mt < 4; ++mt)
#pragma unroll
        for (int nt = 0; nt < 4; ++nt)
          acc[mt][nt] = __builtin_amdgcn_mfma_f32_16x16x32_bf16(af[mt], bfr[nt], acc[mt][nt], 0, 0, 0);
    }

    asm volatile("" ::: "memory");
    __builtin_amdgcn_s_barrier();
    p ^= 1;
  }

  const int row0 = bm * 128 + wr * 64;
  const int rsub = (lane >> 4) << 2;

  if (bn < 4) {   // q half: row-major i8, bias per col
#pragma unroll
    for (int mt = 0; mt < 4; ++mt)
#pragma unroll
      for (int nt = 0; nt < 4; ++nt) {
        int col = bn * 128 + wc * 64 + nt * 16 + lrow;
        float b = bq[col];
#pragma unroll
        for (int r = 0; r < 4; ++r)
          qb8[(long)(row0 + mt * 16 + rsub + r) * 512 + col] = qi8(acc[mt][nt][r] + b);
      }
  } else {        // v half: transposed packed store into vT8[e][m]
#pragma unroll
    for (int mt = 0; mt < 4; ++mt)
#pragma unroll
      for (int nt = 0; nt < 4; ++nt) {
        int e = (bn - 4) * 128 + wc * 64 + nt * 16 + lrow;
        float b = bv[e];
        int rowb = row0 + mt * 16 + rsub;
        uint32_t pk = ((uint32_t)(u8)qi8(acc[mt][nt][0] + b)) |
                      ((uint32_t)(u8)qi8(acc[mt][nt][1] + b) << 8) |
                      ((uint32_t)(u8)qi8(acc[mt][nt][2] + b) << 16) |
                      ((uint32_t)(u8)qi8(acc[mt][nt][3] + b) << 24);
        *(uint32_t*)&vT8[(long)e * 16384 + rowb] = pk;
      }
  }
}

// ---------------- symmetric sigmoid(QQ^T) i8 GEMM -> u8 P ------------------
// 256(M)x128(N) macro-tile; 8 waves (4x2), wave tile 64x64.
// launch_bounds (512,4): (512,6) forces VGPR<=85 -> acc spills (r15). Keep 4.
// Pass-2 merged: both halves bounce in one round, 1 barrier pair (r17).
__global__ __launch_bounds__(512, 4)
void gemm_sym_sig_i8(const signed char* __restrict__ Q, long sQz,
                     u8* __restrict__ P, long sPz) {
  __shared__ u8 lds[49152];                 // 48 KB: staging 384x128 | bounce 256x144

  const int tid  = threadIdx.x;
  const int lane = tid & 63;
  const int w    = tid >> 6;                // 0..7
  const int wr   = w >> 1, wc = w & 1;      // 4 x 2

  const int nwg = (int)gridDim.x;           // 1088
  const int id  = blockIdx.x;
  const int swz = (id & 7) * (nwg >> 3) + (id >> 3);
  const int z   = swz / 272;
  int rem = swz % 272;
  int m = 0;
  while (rem >= 32 - 2 * m) { rem -= 32 - 2 * m; ++m; }
  const int n = 2 * m + rem;                // col block (128-units), n >= 2m

  const int R0 = m * 256;                   // global row base
  const int C0 = n * 128;                   // global col base
  const signed char* Qz = Q + (long)z * sQz;

  const int lrow = lane & 15;
  const int rx   = lane & 7;
  const int srow = lane >> 3;                     // row within 8-row chunk
  const int scol = ((lane & 7) ^ srow) << 4;      // pre-swizzled 16B slot (of 8)

  // staging: 48 chunks x 1KB (8 rows x 128 B); 6 chunks/wave
  const signed char* srcs[6];
#pragma unroll
  for (int c = 0; c < 6; ++c) {
    int row = (w * 6 + c) * 8 + srow;             // 0..383 (A:0-255 | B:256-383)
    srcs[c] = (row < 256)
        ? Qz + (long)(R0 + row) * 512 + scol
        : Qz + (long)(C0 + (row - 256)) * 512 + scol;
  }

  i32x4 acc[4][4] = {};

  for (int kt = 0; kt < 4; ++kt) {                // BK = 128 bytes
#pragma unroll
    for (int c = 0; c < 6; ++c)
      gld_lds(srcs[c] + kt * 128, &lds[(w * 6 + c) * 1024]);
    __syncthreads();

#pragma unroll
    for (int ks = 0; ks < 2; ++ks) {              // two 64B k-slices
      const int sl = ((ks * 4 + (lane >> 4)) ^ rx) << 4;
      i32x4 af[4], bfv[4];
#pragma unroll
      for (int t = 0; t < 4; ++t) {
        af[t]  = *(const i32x4*)&lds[(wr * 64 + t * 16 + lrow) * 128 + sl];
        bfv[t] = *(const i32x4*)&lds[256 * 128 + (wc * 64 + t * 16 + lrow) * 128 + sl];
      }
      __builtin_amdgcn_s_setprio(1);
#pragma unroll
      for (int mt = 0; mt < 4; ++mt)
#pragma unroll
        for (int nt = 0; nt < 4; ++nt)
          acc[mt][nt] = __builtin_amdgcn_mfma_i32_16x16x64_i8(af[mt], bfv[nt], acc[mt][nt], 0, 0, 0);
      __builtin_amdgcn_s_setprio(0);
    }
    __syncthreads();
  }

  u8* Pz = P + (long)z * sPz;
  const int rsub = (lane >> 4) << 2;
  const int rl = wr * 64 + rsub;            // local row base (+mt*16, +r)
  const int cl = wc * 64 + lrow;            // local col base (+nt*16)

  // sigmoid(dequant) -> u8, packed 4 rows per u32. Constant fold:
  // (4/127)^2 * log2(e)/sqrt(512) = 6.324483e-5 -> one mul into exp2 arg.
  uint32_t sbp[4][4];
#pragma unroll
  for (int mt = 0; mt < 4; ++mt)
#pragma unroll
    for (int nt = 0; nt < 4; ++nt) {
      uint32_t pk = 0;
#pragma unroll
      for (int r = 0; r < 4; ++r) {
        float e = __builtin_amdgcn_exp2f((float)acc[mt][nt][r] * -6.324483e-5f);
        float pr = __builtin_amdgcn_rcpf(1.0f + e);
        pk |= (uint32_t)(u8)(int)(pr * 127.f + 0.5f) << (8 * r);
      }
      sbp[mt][nt] = pk;
    }

  const int sslot = tid & 7;               // 16B slot within 128B row
  const int srow2 = tid >> 3;              // 0..63

  // pass 1: normal orientation bounce (256x144) -> dense 16B row stores
#pragma unroll
  for (int mt = 0; mt < 4; ++mt)
#pragma unroll
    for (int nt = 0; nt < 4; ++nt) {
      uint32_t pk = sbp[mt][nt];
#pragma unroll
      for (int r = 0; r < 4; ++r)
        lds[(rl + mt * 16 + r) * 144 + cl + nt * 16] = (u8)(pk >> (8 * r));
    }
  __syncthreads();
#pragma unroll
  for (int j = 0; j < 4; ++j) {            // rows j*64 .. j*64+63; half = j>>1
    int row = j * 64 + srow2;
    if (j < 2 || n > 2 * m) {              // store iff n >= 2m + half
      uint4 v = *(const uint4*)&lds[row * 144 + sslot * 16];
      *(uint4*)&Pz[(long)(R0 + row) * 4096 + C0 + sslot * 16] = v;
    }
  }

  // pass 2 (merged halves): transposed tiles; h=0 -> bounce rows 0-127,
  // h=1 -> rows 128-255. Write iff n > 2m+h; one barrier pair total.
  if (n > 2 * m) {
    __syncthreads();                       // pass-1 bounce reads complete
    const int h = wr >> 1;                 // this wave's half
    if (n > 2 * m + h) {
#pragma unroll
      for (int mt = 0; mt < 4; ++mt)
#pragma unroll
        for (int nt = 0; nt < 4; ++nt)
          *(uint32_t*)&lds[(128 * h + cl + nt * 16) * 144 + (rl - 128 * h + mt * 16)] = sbp[mt][nt];
    }
    __syncthreads();
#pragma unroll
    for (int j = 0; j < 4; ++j) {
      int row = j * 64 + srow2;            // 0..255
      int hh = row >> 7;
      if (n > 2 * m + hh) {
        uint4 v = *(const uint4*)&lds[row * 144 + sslot * 16];
        *(uint4*)&Pz[(long)(C0 + (row & 127)) * 4096 + R0 + 128 * hh + sslot * 16] = v;
      }
    }
  }
}

// ---------------- O = (SP*SV) * P_u8 @ vT_i8^T, i8 MFMA, BK=128 ------------
// 128x128 tile, 4 waves (2x2), wave tile 64x64, 2 blocks/CU (r13: 34 us).
__global__ __launch_bounds__(256, 2)
void gemm_pv_i8(const signed char* __restrict__ A,   // P [4*4096][4096] (u8 vals)
                const signed char* __restrict__ B,   // vT_i8 [512][16384]
                float* __restrict__ C) {             // out [4*4096][512]
  constexpr int NBN = 4, NBM = 32;
  constexpr int TILE = 256 * 128;         // bytes per buffer (32 KB)
  __shared__ signed char lds[2 * TILE];   // 64 KB

  const int tid  = threadIdx.x;
  const int lane = tid & 63;
  const int w    = tid >> 6;              // 0..3
  const int wr   = w >> 1, wc = w & 1;

  const int nwg = (int)gridDim.x;
  const int id  = blockIdx.x;
  const int swz = (id & 7) * (nwg >> 3) + (id >> 3);
  const int bn  = swz % NBN;
  const int t0  = swz / NBN;
  const int bm  = t0 % NBM;
  const int z   = t0 / NBM;

  const signed char* Az = A + (long)z * 4096 * 4096;
  const signed char* Bz = B + (long)z * 4096;
  float* Cz = C + (long)z * 4096 * 512;

  const int lrow = lane & 15;
  const int rx   = lane & 7;
  const int srow = lane >> 3;                     // row within 8-row chunk
  const int scol = ((lane & 7) ^ srow) << 4;      // pre-swizzled 16B slot (of 8)

  // staging: 32 chunks x 1KB (8 rows x 128 B); 8 chunks/wave
  const signed char* srcs[8];
#pragma unroll
  for (int c = 0; c < 8; ++c) {
    int row = (w * 8 + c) * 8 + srow;             // 0..255 (A:0-127 | B:128-255)
    srcs[c] = (row < 128)
        ? Az + (long)(bm * 128 + row) * 4096 + scol
        : Bz + (long)(bn * 128 + (row - 128)) * 16384 + scol;
  }

  i32x4 acc[4][4] = {};

  const int nk = 32;                              // 4096 / 128
#pragma unroll
  for (int c = 0; c < 8; ++c)
    gld_lds(srcs[c], &lds[(w * 8 + c) * 1024]);

  int p = 0;
  for (int kt = 0; kt < nk; ++kt) {
    if (kt + 1 < nk) {
#pragma unroll
      for (int c = 0; c < 8; ++c)
        gld_lds(srcs[c] + (kt + 1) * 128, &lds[(p ^ 1) * TILE + (w * 8 + c) * 1024]);
      asm volatile("s_waitcnt vmcnt(8)" ::: "memory");
    } else {
      asm volatile("s_waitcnt vmcnt(0)" ::: "memory");
    }
    __builtin_amdgcn_s_barrier();
    asm volatile("" ::: "memory");

    const signed char* Al = &lds[p * TILE];
    const signed char* Bl = &lds[p * TILE + 128 * 128];
#pragma unroll
    for (int ks = 0; ks < 2; ++ks) {              // two 64B k-slices
      const int sl = ((ks * 4 + (lane >> 4)) ^ rx) << 4;
      i32x4 af[4], bfv[4];
#pragma unroll
      for (int t = 0; t < 4; ++t) {
        af[t]  = *(const i32x4*)&Al[(wr * 64 + t * 16 + lrow) * 128 + sl];
        bfv[t] = *(const i32x4*)&Bl[(wc * 64 + t * 16 + lrow) * 128 + sl];
      }
      __builtin_amdgcn_s_setprio(1);
#pragma unroll
      for (int mt = 0; mt < 4; ++mt)
#pragma unroll
        for (int nt = 0; nt < 4; ++nt)
          acc[mt][nt] = __builtin_amdgcn_mfma_i32_16x16x64_i8(af[mt], bfv[nt], acc[mt][nt], 0, 0, 0);
      __builtin_amdgcn_s_setprio(0);
    }

    asm volatile("" ::: "memory");
    __builtin_amdgcn_s_barrier();
    p ^= 1;
  }

  // epilogue: scale by SP*SV = (1/127)*(4/127)
  const float SC = 4.0f / 16129.0f;
  const int row0 = bm * 128 + wr * 64;
  const int col0 = bn * 128 + wc * 64;
  const int rsub = (lane >> 4) << 2;
#pragma unroll
  for (int mt = 0; mt < 4; ++mt)
#pragma unroll
    for (int nt = 0; nt < 4; ++nt)
#pragma unroll
      for (int r = 0; r < 4; ++r)
        Cz[(long)(row0 + mt * 16 + rsub + r) * 512 + col0 + nt * 16 + lrow] =
            SC * (float)acc[mt][nt][r];
}

// ---------------- launch ----------------
extern "C" void kernel_launch(void* const* d_in, const int* in_sizes, int n_in,
                              void* d_out, int out_size, void* d_ws, size_t ws_size,
                              hipStream_t stream) {
  const float* x  = (const float*)d_in[0];   // [4,4096,512]
  const float* Wq = (const float*)d_in[1];   // [512,512]
  const float* bq = (const float*)d_in[2];   // [512]
  const float* Wv = (const float*)d_in[3];   // [512,512]
  const float* bv = (const float*)d_in[4];   // [512]
  float* out = (float*)d_out;                // [4,4096,512] f32

  // workspace carve (~114 MB)
  char* wsb = (char*)d_ws;
  u16* xb  = (u16*)wsb;                                   // [16384][512] bf16  32 MB
  signed char* qb8 = (signed char*)(wsb + 33554432);      // [16384][512] i8     8 MB
  signed char* vT8 = (signed char*)(wsb + 41943040);      // [512][16384] i8     8 MB
  u16* wqb = (u16*)(wsb + 50331648);                      // [512][512] bf16
  u16* wvb = (u16*)(wsb + 50855936);                      // [512][512] bf16
  u8*  P8  = (u8*)(wsb + 51380224);                       // [4][4096][4096] u8 64 MB

  conv_kernel<<<8704, 256, 0, stream>>>(x, Wq, Wv, xb, wqb, wvb);

  // fused: q8 = qi8(xb Wq^T + bq), vT8 = qi8(xb Wv^T + bv)^T
  gemm_proj<<<1024, 256, 0, stream>>>(xb, wqb, wvb, bq, bv, qb8, vT8);

  // P = round(127*sigmoid((4/127)^2 * q8 q8^T / sqrt(512))) u8, symmetric
  gemm_sym_sig_i8<<<1088, 512, 0, stream>>>(qb8, (long)4096 * 512,
                                            P8, (long)4096 * 4096);

  // O = (1/127)*(4/127) * P @ v
  gemm_pv_i8<<<512, 256, 0, stream>>>((const signed char*)P8, vT8, out);
}